// Round 6
// baseline (82.920 us; speedup 1.0000x reference)
//
#include <hip/hip_runtime.h>

// FieldWeightedFactorizationMachine forward — round 5: intra-wave pipelining.
// B=32768 rows; F=39 fields; D=64 dims; V=1e6 vocab.
// One 64-lane wave computes FW_RPW=4 rows, double-buffered: while row k's
// 780-FMA interaction compute runs, row k+1's 39 non-temporal gathers are in
// flight. All row indices loaded up-front (one coalesced load per row) so no
// vmcnt(0) drain sits between gather bursts. Buffers va/vb statically indexed.

#define FW_B 32768
#define FW_F 39
#define FW_D 64
#define FW_RPW 4   // rows per wave (pipelined)
#define FW_WPB 4   // waves per block (256 threads)

__global__ __launch_bounds__(256) void fwfm_kernel(
    const int*   __restrict__ x,      // (B, F)
    const float* __restrict__ emb,    // (V, D)
    const float* __restrict__ bias,   // (V, 1)
    const float* __restrict__ W,      // (F, F)
    const float* __restrict__ w0,     // (1,)
    float*       __restrict__ out)    // (B,)
{
    const int wave = threadIdx.x >> 6;
    const int lane = threadIdx.x & 63;            // dim d
    const int wid  = blockIdx.x * FW_WPB + wave;
    const int row0 = wid * FW_RPW;
    if (row0 >= FW_B) return;

    const int xl = (lane < FW_F) ? lane : (FW_F - 1);

    // All 4 rows' indices (lane i -> idx_i) + bias contributions up-front:
    // one vmcnt drain total, then gather bursts never wait on index loads.
    int   idxs[FW_RPW];
    float bs  [FW_RPW];
    #pragma unroll
    for (int k = 0; k < FW_RPW; ++k)
        idxs[k] = x[(row0 + k) * FW_F + xl];
    #pragma unroll
    for (int k = 0; k < FW_RPW; ++k)
        bs[k] = (lane < FW_F) ? bias[(unsigned)idxs[k]] : 0.0f;

    float va[FW_F], vb[FW_F];   // double buffer, statically indexed only

#define FW_GATHER(buf, k)                                                    \
    {                                                                        \
        _Pragma("unroll")                                                    \
        for (int i = 0; i < FW_F; ++i) {                                     \
            const int si = __shfl(idxs[k], i, 64);                           \
            const unsigned off = (unsigned)si * (unsigned)FW_D + (unsigned)lane; \
            buf[i] = __builtin_nontemporal_load(emb + off);                  \
        }                                                                    \
    }

#define FW_COMPUTE(buf, k)                                                   \
    {                                                                        \
        float part = bs[k];                                                  \
        _Pragma("unroll")                                                    \
        for (int i = 0; i < FW_F - 1; ++i) {                                 \
            float s = 0.0f;                                                  \
            _Pragma("unroll")                                                \
            for (int j = i + 1; j < FW_F; ++j)                               \
                s = fmaf(W[i * FW_F + j], buf[j], s);                        \
            part = fmaf(buf[i], s, part);                                    \
        }                                                                    \
        _Pragma("unroll")                                                    \
        for (int off = 32; off >= 1; off >>= 1)                              \
            part += __shfl_xor(part, off, 64);                               \
        if (lane == 0) out[row0 + (k)] = w0[0] + part;                       \
    }

    // 2-deep pipeline: compute(k) overlaps gather(k+1).
    FW_GATHER(va, 0)
    FW_GATHER(vb, 1)
    FW_COMPUTE(va, 0)
    FW_GATHER(va, 2)
    FW_COMPUTE(vb, 1)
    FW_GATHER(vb, 3)
    FW_COMPUTE(va, 2)
    FW_COMPUTE(vb, 3)

#undef FW_GATHER
#undef FW_COMPUTE
}

extern "C" void kernel_launch(void* const* d_in, const int* in_sizes, int n_in,
                              void* d_out, int out_size, void* d_ws, size_t ws_size,
                              hipStream_t stream) {
    const int*   x    = (const int*)  d_in[0];
    const float* emb  = (const float*)d_in[1];
    const float* bias = (const float*)d_in[2];
    const float* W    = (const float*)d_in[3];
    const float* w0   = (const float*)d_in[4];
    float* out        = (float*)d_out;

    const int rows_per_block = FW_WPB * FW_RPW;    // 16
    const int grid = (FW_B + rows_per_block - 1) / rows_per_block;  // 2048
    fwfm_kernel<<<grid, 256, 0, stream>>>(x, emb, bias, W, w0, out);
}

// Round 8
// 80.449 us; speedup vs baseline: 1.0307x; 1.0307x over previous
//
#include <hip/hip_runtime.h>

// FieldWeightedFactorizationMachine forward — round 7: dwordx4 gathers + LDS transpose.
// (round-6 design; compile fix: native clang vector type for nontemporal_load)
// B=32768 rows; F=39 fields; D=64 dims; V=1e6 vocab.
// One wave per row. Gather phase: lane (g,c)=(lane>>4, lane&15); instruction
// t in [0,10) loads field f=4t+g, dims [4c..4c+3] as float4 (non-temporal)
// -> 10 vmem instructions per row (1KB each) instead of 39, cutting per-CU
// outstanding-request entries 4x for the same bytes. Rows land in a per-wave
// private LDS tile [39][64] (conflict-free both phases; no barrier needed).
// Compute phase: lane = dim d, identical FMA chain to round 3.

#define FW_B 32768
#define FW_F 39
#define FW_D 64

typedef float fvec4 __attribute__((ext_vector_type(4)));

__global__ __launch_bounds__(256, 4) void fwfm_kernel(
    const int*   __restrict__ x,      // (B, F)
    const float* __restrict__ emb,    // (V, D)
    const float* __restrict__ bias,   // (V, 1)
    const float* __restrict__ W,      // (F, F)
    const float* __restrict__ w0,     // (1,)
    float*       __restrict__ out)    // (B,)
{
    __shared__ float lds[4][FW_F * FW_D];          // 4 waves x 9984B = 39.9KB

    const int wave = threadIdx.x >> 6;
    const int lane = threadIdx.x & 63;             // compute phase: dim d
    const int row  = blockIdx.x * 4 + wave;
    if (row >= FW_B) return;

    const int g = lane >> 4;                       // row-group 0..3
    const int c = lane & 15;                       // float4 chunk 0..15

    // One coalesced idx load: lane i (i<39) holds idx_i; clamp tail lanes.
    const int xl   = (lane < FW_F) ? lane : (FW_F - 1);
    const int idxv = x[row * FW_F + xl];

    // Per-lane bias contribution (temporal — want the 4MB table L2-resident).
    float part = (lane < FW_F) ? bias[(unsigned)idxv] : 0.0f;

    float* __restrict__ wl = lds[wave];

    // Gather: 10 x (64 lanes x 16B) = 4 embedding rows per instruction.
    #pragma unroll
    for (int t = 0; t < 10; ++t) {
        const int f  = 4 * t + g;
        const int fc = (f < FW_F) ? f : (FW_F - 1);
        const int si = __shfl(idxv, fc, 64);       // uniform CF; bpermute
        if (f < FW_F) {
            const fvec4 v4 = __builtin_nontemporal_load(
                reinterpret_cast<const fvec4*>(
                    emb + (unsigned)si * (unsigned)FW_D + 4u * (unsigned)c));
            *reinterpret_cast<fvec4*>(wl + f * FW_D + 4 * c) = v4;
        }
    }
    // No __syncthreads: each wave reads only its own LDS tile; within-wave
    // vm/ds ordering is enforced by compiler-inserted waitcnts.

    // Transposed read: lane = dim d; 2 lanes/bank = conflict-free.
    float v[FW_F];
    #pragma unroll
    for (int i = 0; i < FW_F; ++i)
        v[i] = wl[i * FW_D + lane];

    // Upper-triangular weighted pairwise products for this lane's dim.
    // W reads are wave-uniform with compile-time offsets -> scalar loads.
    #pragma unroll
    for (int i = 0; i < FW_F - 1; ++i) {
        float s = 0.0f;
        #pragma unroll
        for (int j = i + 1; j < FW_F; ++j)
            s = fmaf(W[i * FW_F + j], v[j], s);
        part = fmaf(v[i], s, part);
    }

    // Reduce (interactions + bias) over the 64 lanes.
    #pragma unroll
    for (int off = 32; off >= 1; off >>= 1)
        part += __shfl_xor(part, off, 64);

    if (lane == 0)
        out[row] = w0[0] + part;
}

extern "C" void kernel_launch(void* const* d_in, const int* in_sizes, int n_in,
                              void* d_out, int out_size, void* d_ws, size_t ws_size,
                              hipStream_t stream) {
    const int*   x    = (const int*)  d_in[0];
    const float* emb  = (const float*)d_in[1];
    const float* bias = (const float*)d_in[2];
    const float* W    = (const float*)d_in[3];
    const float* w0   = (const float*)d_in[4];
    float* out        = (float*)d_out;

    const int rows_per_block = 4;                  // 4 waves x 1 row each
    const int grid = (FW_B + rows_per_block - 1) / rows_per_block;
    fwfm_kernel<<<grid, 256, 0, stream>>>(x, emb, bias, W, w0, out);
}

// Round 9
// 74.120 us; speedup vs baseline: 1.1187x; 1.0854x over previous
//
#include <hip/hip_runtime.h>

// FieldWeightedFactorizationMachine forward — round 8: revert to round-3 best.
// B=32768 rows; F=39 fields; D=64 dims; V=1e6 vocab.
// One 64-lane wave per row: lane = dim d.
// - Embedding gathers non-temporal (random 327MB stream, zero reuse: skip L2
//   allocation, keep the 4MB bias table L2-resident). Measured best: 73.7us.
// - Bias: lane i<39 gathers bias[idx_i]; folded into the shfl reduce.
// - saddr-form gathers via 32-bit zext offsets; launch_bounds(256,4).

#define FW_B 32768
#define FW_F 39
#define FW_D 64

__global__ __launch_bounds__(256, 4) void fwfm_kernel(
    const int*   __restrict__ x,      // (B, F)
    const float* __restrict__ emb,    // (V, D)
    const float* __restrict__ bias,   // (V, 1)
    const float* __restrict__ W,      // (F, F)
    const float* __restrict__ w0,     // (1,)
    float*       __restrict__ out)    // (B,)
{
    const int wave = threadIdx.x >> 6;            // 0..3
    const int lane = threadIdx.x & 63;            // dim d
    const int row  = blockIdx.x * 4 + wave;
    if (row >= FW_B) return;

    // Per-lane bias contribution: lane i (i<39) gathers bias[idx_i].
    float part = 0.0f;
    if (lane < FW_F) {
        const int idxl = x[row * FW_F + lane];
        part = bias[(unsigned)idxl];
    }

    // Gather embeddings: uniform idx load, 32-bit zext offset (saddr-form
    // global_load), NON-TEMPORAL so the random stream bypasses L2 allocation.
    float v[FW_F];
    #pragma unroll
    for (int i = 0; i < FW_F; ++i) {
        const int si = x[row * FW_F + i];                   // wave-uniform
        const unsigned off = (unsigned)si * (unsigned)FW_D + (unsigned)lane;
        v[i] = __builtin_nontemporal_load(emb + off);
    }

    // Upper-triangular weighted pairwise products for this lane's dim.
    // W reads are wave-uniform with compile-time offsets -> scalar loads.
    #pragma unroll
    for (int i = 0; i < FW_F - 1; ++i) {
        float s = 0.0f;
        #pragma unroll
        for (int j = i + 1; j < FW_F; ++j)
            s = fmaf(W[i * FW_F + j], v[j], s);
        part = fmaf(v[i], s, part);
    }

    // Reduce (interactions + bias) over the 64 lanes.
    #pragma unroll
    for (int off = 32; off >= 1; off >>= 1)
        part += __shfl_xor(part, off, 64);

    if (lane == 0)
        out[row] = w0[0] + part;
}

extern "C" void kernel_launch(void* const* d_in, const int* in_sizes, int n_in,
                              void* d_out, int out_size, void* d_ws, size_t ws_size,
                              hipStream_t stream) {
    const int*   x    = (const int*)  d_in[0];
    const float* emb  = (const float*)d_in[1];
    const float* bias = (const float*)d_in[2];
    const float* W    = (const float*)d_in[3];
    const float* w0   = (const float*)d_in[4];
    float* out        = (float*)d_out;

    const int rows_per_block = 4;                  // 4 waves x 64 lanes
    const int grid = (FW_B + rows_per_block - 1) / rows_per_block;
    fwfm_kernel<<<grid, 256, 0, stream>>>(x, emb, bias, W, w0, out);
}